// Round 10
// baseline (195.776 us; speedup 1.0000x reference)
//
#include <hip/hip_runtime.h>

#define NQ     14
#define DIM    16384
#define NPAR   196
#define NCLS   10
#define NGT    56     // gate table: rounds 1..4 (round 0 + chain 0 folded into init)
#define NCOEF  70     // all 70 coefficient sets (init uses slots 0..13)
#define NBLK   256

// ---------------- compile-time frame/gate tables ----------------
// Stored state d[h] = s_ref[A(h)], A linear over GF(2)^14.
//  - layer-0 rotations + CNOT chain 0 folded into analytic product init
//    (identity frame start): d[h] = prod_q U_q[bit_{13-q}(h^(h>>1))][0]
//  - CNOT chain:  s' = s o g, g(i)=i^(i>>1)  =>  m[bp]^=m[bp-1]; u = suffix-xor
//  - rotation on ref bit bp: pair h <-> h^m[bp], role = parity(h & u[bp])
//  - physical relabel sigma (bits {12,13}<->{6,7}) => m,u <- sigma(m),sigma(u)
// Layout: h = p(2b,13:12) | w(3b,11:9) | k(3b,8:6) | lane(6b,5:0)
// 4 rounds (r=1..4): phase-1 gates (m avoids bits 12,13), sigma (global
// exchange), phase-2 gates (local after sigma). 4 exchanges total.
struct GateInfo { int m; int u; int slot; };
struct Tables { GateInfo g[NGT]; int mu[NQ]; int swap_at[4]; bool valid; };

constexpr unsigned swapbits(unsigned v) {   // swap bits {6,7} <-> {12,13}
    return (v & ~0x30C0u) | ((v & 0xC0u) << 6) | ((v >> 6) & 0xC0u);
}

constexpr Tables make_tables() {
    Tables T{};
    T.valid = true;
    unsigned m[NQ] = {}, u[NQ] = {};
    for (int i = 0; i < NQ; ++i) { m[i] = 1u << i; u[i] = 1u << i; }
    int gi = 0;
    for (int r = 1; r <= 4; ++r) {
        bool done[NQ] = {};
        for (int q = 0; q < NQ; ++q) {            // phase 1: m avoids bits 12,13
            int bp = 13 - q;
            if ((m[bp] & 0x3000u) == 0u) {
                T.g[gi].m = (int)m[bp]; T.g[gi].u = (int)u[bp];
                T.g[gi].slot = r * 14 + q;
                done[q] = true; ++gi;
            }
        }
        T.swap_at[r - 1] = gi;
        if (r > 1 && T.swap_at[r - 1] <= T.swap_at[r - 2]) T.valid = false;
        for (int i = 0; i < NQ; ++i) { m[i] = swapbits(m[i]); u[i] = swapbits(u[i]); }
        for (int q = 0; q < NQ; ++q) {            // phase 2: local after sigma
            if (!done[q]) {
                int bp = 13 - q;
                if ((m[bp] & 0x3000u) != 0u) T.valid = false;
                T.g[gi].m = (int)m[bp]; T.g[gi].u = (int)u[bp];
                T.g[gi].slot = r * 14 + q;
                ++gi;
            }
        }
        if (r < 4) {                              // chains 1..3 retabulation
            for (int bp = 13; bp >= 1; --bp) m[bp] ^= m[bp - 1];
            unsigned acc = 0;
            for (int bp = 13; bp >= 0; --bp) { acc ^= u[bp]; u[bp] = acc; }
        }
    }
    if (gi != NGT) T.valid = false;
    for (int q = 0; q < NQ; ++q) T.mu[q] = (int)u[13 - q];
    return T;
}
constexpr Tables TAB = make_tables();
static_assert(TAB.valid, "gate schedule construction failed");

constexpr int seg_lo(int s) { return s == 0 ? 0 : TAB.swap_at[s - 1]; }
constexpr int seg_hi(int s) { return s < 4 ? TAB.swap_at[s] : NGT; }

// ---------------- per-BLOCK-fence grid barrier ----------------
// Round 8 lesson: per-wave __threadfence = L2 wb/inv per wave (~75us/barrier).
// Round 9 lesson: agent-scope atomic data path = ~480 GB/s (coherence point).
// Here: exchange data uses PLAIN cached stores/loads (write-through L1 -> L2);
// __syncthreads drains all waves' stores into L2; then ONE thread per block
// fences (cache-wide L2 writeback / L1+L2 invalidate) around the arrive/spin.
__device__ __forceinline__ void gbar(unsigned* cnt_ep) {
    asm volatile("s_waitcnt vmcnt(0)" ::: "memory");
    __syncthreads();                 // all waves' stores are in L2
    if (threadIdx.x == 0) {
        __threadfence();             // release: one L2 writeback per block
        __hip_atomic_fetch_add(cnt_ep, 1u, __ATOMIC_RELEASE,
                               __HIP_MEMORY_SCOPE_AGENT);
        while (__hip_atomic_load(cnt_ep, __ATOMIC_RELAXED,
                                 __HIP_MEMORY_SCOPE_AGENT) < (unsigned)NBLK)
            __builtin_amdgcn_s_sleep(2);
        __threadfence();             // acquire: one L1/L2 invalidate per block
    }
    __syncthreads();                 // block reads only after tid0's invalidate
}

// Apply gates [seg_lo(SEG), seg_hi(SEG)) to the 8 register amps.
template<int SEG>
__device__ __forceinline__ void do_gates(float (&ar)[8], float (&ai)[8],
    const float (*uc)[8], float* lds_r, float* lds_i, int tid, int hbase)
{
    constexpr int LO = seg_lo(SEG);
    constexpr int HI = seg_hi(SEG);
    #pragma unroll
    for (int g = LO; g < HI; ++g) {
        const int m = TAB.g[g].m, u = TAB.g[g].u;
        const float4 c0 = *(const float4*)&uc[TAB.g[g].slot][0];  // {00r,00i,01r,01i}
        const float4 c1 = *(const float4*)&uc[TAB.g[g].slot][4];  // {10r,10i,11r,11i}
        const bool rb = (__popc(hbase & u) & 1) != 0;
        const float D0r = rb ? c1.z : c0.x, D0i = rb ? c1.w : c0.y;
        const float O0r = rb ? c1.x : c0.z, O0i = rb ? c1.y : c0.w;
        const float D1r = rb ? c0.x : c1.z, D1i = rb ? c0.y : c1.w;
        const float O1r = rb ? c0.z : c1.x, O1i = rb ? c0.w : c1.y;

        const int ml = m & 63;            // lane part
        const int mk = (m >> 6) & 7;      // reg part
        const int mw = (m >> 9) & 7;      // wave part
        float pr[8], pim[8];
        if (mw == 0 && ml == 0) {
            #pragma unroll
            for (int k = 0; k < 8; ++k) { pr[k] = ar[k ^ mk]; pim[k] = ai[k ^ mk]; }
        } else if (mw == 0) {
            #pragma unroll
            for (int k = 0; k < 8; ++k) {
                pr[k]  = __shfl_xor(ar[k ^ mk], ml, 64);
                pim[k] = __shfl_xor(ai[k ^ mk], ml, 64);
            }
        } else {
            const int tm = (mw << 6) | ml;
            __syncthreads();   // WAR: prior readers of lds done
            #pragma unroll
            for (int k = 0; k < 8; ++k) {
                lds_r[k * 512 + tid] = ar[k];
                lds_i[k * 512 + tid] = ai[k];
            }
            __syncthreads();
            #pragma unroll
            for (int k = 0; k < 8; ++k) {
                pr[k]  = lds_r[(k ^ mk) * 512 + (tid ^ tm)];
                pim[k] = lds_i[(k ^ mk) * 512 + (tid ^ tm)];
            }
        }
        const int ku = (u >> 6) & 7;
        #pragma unroll
        for (int k = 0; k < 8; ++k) {
            const int cls = __popc(k & ku) & 1;   // compile-time per k
            const float Dr = cls ? D1r : D0r, Di = cls ? D1i : D0i;
            const float Or = cls ? O1r : O0r, Oi = cls ? O1i : O0i;
            float nr = Dr * ar[k] - Di * ai[k] + Or * pr[k] - Oi * pim[k];
            float ni = Dr * ai[k] + Di * ar[k] + Or * pim[k] + Oi * pr[k];
            ar[k] = nr; ai[k] = ni;
        }
    }
}

// ============ single launch: 256 blocks x 512 threads ============
// h = p<<12 | w<<9 | k<<6 | l ;  e = blk>>2, p = blk&3, w = tid>>6, l = tid&63
// Boundary sigma ({12,13}<->{6,7}): amps with (k&3)==p are fixed points (stay in
// registers). Others: writer slot (k&3)<<12 | w<<9 | (k>>2)<<8 | p<<6 | l,
// plain cached stores/loads (coherence via gbar's per-block fences). Coalesced.
__global__ void __launch_bounds__(512, 2)
qvc_persist(const float* __restrict__ x, const float* __restrict__ W,
            const float* __restrict__ bias, float2* __restrict__ bufA,
            float2* __restrict__ bufB, float* __restrict__ part,
            float* __restrict__ out, unsigned* __restrict__ bar)
{
    __shared__ __align__(16) float uc[NCOEF][8];
    __shared__ float lds_r[8 * 512];
    __shared__ float lds_i[8 * 512];
    __shared__ float red[8][NQ];

    const int blk = blockIdx.x;
    const int e = blk >> 2, p = blk & 3;
    const int tid = threadIdx.x;
    const int w = tid >> 6, l = tid & 63;
    const int hbase = (p << 12) | (w << 9) | l;   // h minus the k bits
    const float* xb = x + e * NPAR;

    // ---- all 70 gate-coefficient sets, one gate per thread ----
    if (tid < NCOEF) {
        const int layer = tid / 14, q = tid % 14;
        const int pidx = (layer < 4) ? layer * 42 + q * 3 : 168 + q * 2;
        float a1 = 0.5f * xb[pidx], a2 = 0.5f * xb[pidx + 1];
        float s1, c1, s2, c2;
        sincosf(a1, &s1, &c1);
        sincosf(a2, &s2, &c2);
        float A00r =  c2 * c1, A00i =  s2 * s1;
        float A01r = -s2 * c1, A01i = -c2 * s1;
        float A10r =  s2 * c1, A10i = -c2 * s1;
        float A11r =  c2 * c1, A11i = -s2 * s1;
        float U0, U1, U2, U3, U4, U5, U6, U7;
        if (layer < 4) {
            float a3 = 0.5f * xb[pidx + 2]; float s3, c3; sincosf(a3, &s3, &c3);
            U0 = c3 * A00r + s3 * A00i; U1 = c3 * A00i - s3 * A00r;
            U2 = c3 * A01r + s3 * A01i; U3 = c3 * A01i - s3 * A01r;
            U4 = c3 * A10r - s3 * A10i; U5 = c3 * A10i + s3 * A10r;
            U6 = c3 * A11r - s3 * A11i; U7 = c3 * A11i + s3 * A11r;
        } else {
            U0 = A00r; U1 = A00i; U2 = A01r; U3 = A01i;
            U4 = A10r; U5 = A10i; U6 = A11r; U7 = A11i;
        }
        uc[tid][0] = U0; uc[tid][1] = U1; uc[tid][2] = U2; uc[tid][3] = U3;
        uc[tid][4] = U4; uc[tid][5] = U5; uc[tid][6] = U6; uc[tid][7] = U7;
    }
    __syncthreads();

    // ---- analytic init: d[h] = prod_q U_q[bit_{13-q}(h^(h>>1))][0] ----
    // (layer-0 rotations + CNOT chain 0; identity frame afterwards)
    float ar[8], ai[8];
    {
        // bits 13..9 of gh = h^(h>>1) are k-invariant: hoist those 5 factors
        const int ghi = (hbase ^ (hbase >> 1)) >> 9;   // bits 13:9 (hbase has bits 9+ fixed)
        float br = 1.0f, bi = 0.0f;
        #pragma unroll
        for (int q = 0; q < 5; ++q) {                  // q=0..4 -> bp=13..9
            const int b = (ghi >> (4 - q)) & 1;
            const float fr = b ? uc[q][4] : uc[q][0];
            const float fi = b ? uc[q][5] : uc[q][1];
            const float nr = br * fr - bi * fi;
            const float ni = br * fi + bi * fr;
            br = nr; bi = ni;
        }
        #pragma unroll
        for (int k = 0; k < 8; ++k) {
            const int h  = hbase | (k << 6);
            const int gh = h ^ (h >> 1);
            float re = br, im = bi;
            #pragma unroll
            for (int q = 5; q < NQ; ++q) {             // bp = 13-q = 8..0
                const int b = (gh >> (13 - q)) & 1;
                const float fr = b ? uc[q][4] : uc[q][0];
                const float fi = b ? uc[q][5] : uc[q][1];
                const float nr = re * fr - im * fi;
                const float ni = re * fi + im * fr;
                re = nr; im = ni;
            }
            ar[k] = re; ai[k] = im;
        }
    }

    // sigma exchange: skip fixed points (k&3)==p; plain cached ops
    auto store_sigma = [&](float2* buf) {
        #pragma unroll
        for (int k = 0; k < 8; ++k) {
            if ((k & 3) == p) continue;          // fixed point: stays in ar/ai
            const int idx = (e << 14) | ((k & 3) << 12) | (w << 9) |
                            ((k >> 2) << 8) | (p << 6) | l;
            buf[idx] = make_float2(ar[k], ai[k]);
        }
    };
    auto load_linear = [&](const float2* buf) {
        #pragma unroll
        for (int k = 0; k < 8; ++k) {
            if ((k & 3) == p) continue;          // fixed point: already in ar/ai
            float2 v = buf[(e << 14) | hbase | (k << 6)];
            ar[k] = v.x; ai[k] = v.y;
        }
    };

    do_gates<0>(ar, ai, uc, lds_r, lds_i, tid, hbase);
    store_sigma(bufA);
    gbar(bar + 0 * 16);
    load_linear(bufA);

    do_gates<1>(ar, ai, uc, lds_r, lds_i, tid, hbase);
    store_sigma(bufB);
    gbar(bar + 1 * 16);
    load_linear(bufB);

    do_gates<2>(ar, ai, uc, lds_r, lds_i, tid, hbase);
    store_sigma(bufA);
    gbar(bar + 2 * 16);
    load_linear(bufA);

    do_gates<3>(ar, ai, uc, lds_r, lds_i, tid, hbase);
    store_sigma(bufB);
    gbar(bar + 3 * 16);
    load_linear(bufB);

    do_gates<4>(ar, ai, uc, lds_r, lds_i, tid, hbase);

    // ---- measurement partials: E_q = sum |amp|^2 * (-1)^parity(h & mu[q]) ----
    {
        float eq[NQ];
        #pragma unroll
        for (int q = 0; q < NQ; ++q) eq[q] = 0.0f;
        #pragma unroll
        for (int k = 0; k < 8; ++k) {
            float p2 = ar[k] * ar[k] + ai[k] * ai[k];
            #pragma unroll
            for (int q = 0; q < NQ; ++q) {
                if (__popc(k & ((TAB.mu[q] >> 6) & 7)) & 1) eq[q] -= p2; else eq[q] += p2;
            }
        }
        #pragma unroll
        for (int q = 0; q < NQ; ++q) {
            float v = (__popc(hbase & TAB.mu[q]) & 1) ? -eq[q] : eq[q];
            #pragma unroll
            for (int off = 32; off > 0; off >>= 1) v += __shfl_down(v, off, 64);
            eq[q] = v;
        }
        if (l == 0) {
            #pragma unroll
            for (int q = 0; q < NQ; ++q) red[w][q] = eq[q];
        }
        __syncthreads();
        if (tid < NQ) {
            float s = 0.0f;
            #pragma unroll
            for (int ww = 0; ww < 8; ++ww) s += red[ww][tid];
            part[(e * 4 + p) * NQ + tid] = s;
        }
    }
    gbar(bar + 4 * 16);

    // ---- head: blocks 0..63, one element each ----
    if (blk < 64 && tid < NCLS) {
        const int e2 = blk, c = tid;
        float acc = bias[c];
        const float* pe = part + e2 * 4 * NQ;
        #pragma unroll
        for (int q = 0; q < NQ; ++q) {
            float eqv = pe[q] + pe[NQ + q] + pe[2 * NQ + q] + pe[3 * NQ + q];
            acc += W[c * NQ + q] * eqv;
        }
        out[e2 * NCLS + c] = acc;
    }
}

extern "C" void kernel_launch(void* const* d_in, const int* in_sizes, int n_in,
                              void* d_out, int out_size, void* d_ws, size_t ws_size,
                              hipStream_t stream)
{
    const float* x    = (const float*)d_in[0];   // (64, 196)
    const float* W    = (const float*)d_in[1];   // (10, 14)
    const float* bias = (const float*)d_in[2];   // (10,)
    float*       out  = (float*)d_out;           // (64, 10)

    const size_t state_elems = (size_t)64 * DIM;          // float2 each
    float2*   bufA = (float2*)d_ws;
    float2*   bufB = bufA + state_elems;
    float*    part = (float*)(bufB + state_elems);        // 64*4*14 floats
    unsigned* bar  = (unsigned*)((char*)d_ws + 2 * state_elems * sizeof(float2) + 16384);
    (void)ws_size;  // observed 268 MB >> ~16.1 MB needed

    // zero the 5 per-epoch barrier counters every call (graph memset node)
    hipMemsetAsync(bar, 0, 512, stream);

    void* args[] = { (void*)&x, (void*)&W, (void*)&bias,
                     (void*)&bufA, (void*)&bufB, (void*)&part,
                     (void*)&out, (void*)&bar };
    hipLaunchCooperativeKernel((void*)qvc_persist, dim3(NBLK), dim3(512),
                               args, 0, stream);
}

// Round 12
// 68.461 us; speedup vs baseline: 2.8597x; 2.8597x over previous
//
#include <hip/hip_runtime.h>

#define NQ     14
#define DIM    16384
#define NPAR   196
#define NCLS   10
#define NGT    56     // gate table: rounds 1..4 (layer 0 + chain 0 folded into init)
#define NCOEF  70     // all 70 coefficient sets (init uses slots 0..13)

// ---------------- compile-time frame/gate tables (verified round 10) ----------------
// Stored state d[h] = s_ref[A(h)], A linear over GF(2)^14.
//  - layer-0 rotations + CNOT chain 0 folded into analytic product init
//    (identity frame afterwards): d[h] = prod_q U_q[bit_{13-q}(h^(h>>1))][0]
//  - CNOT chain:  s' = s o g, g(i)=i^(i>>1)  =>  m[bp]^=m[bp-1]; u = suffix-xor
//  - rotation on ref bit bp: pair h <-> h^m[bp], role = parity(h & u[bp])
//  - physical relabel sigma (bits {12,13}<->{6,7}) => m,u <- sigma(m),sigma(u)
// Layout: h = p(2b,13:12) | w(3b,11:9) | k(3b,8:6) | lane(6b,5:0)
// 4 rounds (r=1..4): phase-1 gates (m avoids bits 12,13), sigma (realized as the
// coalesced inter-kernel exchange), phase-2 gates (local after sigma). 4 boundaries.
struct GateInfo { int m; int u; int slot; };
struct Tables { GateInfo g[NGT]; int mu[NQ]; int swap_at[4]; bool valid; };

constexpr unsigned swapbits(unsigned v) {   // swap bits {6,7} <-> {12,13}
    return (v & ~0x30C0u) | ((v & 0xC0u) << 6) | ((v >> 6) & 0xC0u);
}

constexpr Tables make_tables() {
    Tables T{};
    T.valid = true;
    unsigned m[NQ] = {}, u[NQ] = {};
    for (int i = 0; i < NQ; ++i) { m[i] = 1u << i; u[i] = 1u << i; }
    int gi = 0;
    for (int r = 1; r <= 4; ++r) {
        bool done[NQ] = {};
        for (int q = 0; q < NQ; ++q) {            // phase 1: m avoids bits 12,13
            int bp = 13 - q;
            if ((m[bp] & 0x3000u) == 0u) {
                T.g[gi].m = (int)m[bp]; T.g[gi].u = (int)u[bp];
                T.g[gi].slot = r * 14 + q;
                done[q] = true; ++gi;
            }
        }
        T.swap_at[r - 1] = gi;
        if (r > 1 && T.swap_at[r - 1] <= T.swap_at[r - 2]) T.valid = false;
        for (int i = 0; i < NQ; ++i) { m[i] = swapbits(m[i]); u[i] = swapbits(u[i]); }
        for (int q = 0; q < NQ; ++q) {            // phase 2: local after sigma
            if (!done[q]) {
                int bp = 13 - q;
                if ((m[bp] & 0x3000u) != 0u) T.valid = false;
                T.g[gi].m = (int)m[bp]; T.g[gi].u = (int)u[bp];
                T.g[gi].slot = r * 14 + q;
                ++gi;
            }
        }
        if (r < 4) {                              // chains 1..3 retabulation
            for (int bp = 13; bp >= 1; --bp) m[bp] ^= m[bp - 1];
            unsigned acc = 0;
            for (int bp = 13; bp >= 0; --bp) { acc ^= u[bp]; u[bp] = acc; }
        }
    }
    if (gi != NGT) T.valid = false;
    for (int q = 0; q < NQ; ++q) T.mu[q] = (int)u[13 - q];
    return T;
}
constexpr Tables TAB = make_tables();
static_assert(TAB.valid, "gate schedule construction failed");
static_assert(TAB.swap_at[0] > 0 && TAB.swap_at[3] < NGT, "segment layout");

constexpr int seg_lo(int s) { return s == 0 ? 0 : TAB.swap_at[s - 1]; }
constexpr int seg_hi(int s) { return s < 4 ? TAB.swap_at[s] : NGT; }

// Apply gates [seg_lo(SEG), seg_hi(SEG)) to the 8 register amps.
template<int SEG>
__device__ __forceinline__ void do_gates(float (&ar)[8], float (&ai)[8],
    const float (*uc)[8], float* lds_r, float* lds_i, int tid, int hbase)
{
    constexpr int LO = seg_lo(SEG);
    constexpr int HI = seg_hi(SEG);
    #pragma unroll
    for (int g = LO; g < HI; ++g) {
        const int m = TAB.g[g].m, u = TAB.g[g].u;
        const float4 c0 = *(const float4*)&uc[TAB.g[g].slot][0];  // {00r,00i,01r,01i}
        const float4 c1 = *(const float4*)&uc[TAB.g[g].slot][4];  // {10r,10i,11r,11i}
        const bool rb = (__popc(hbase & u) & 1) != 0;
        const float D0r = rb ? c1.z : c0.x, D0i = rb ? c1.w : c0.y;
        const float O0r = rb ? c1.x : c0.z, O0i = rb ? c1.y : c0.w;
        const float D1r = rb ? c0.x : c1.z, D1i = rb ? c0.y : c1.w;
        const float O1r = rb ? c0.z : c1.x, O1i = rb ? c0.w : c1.y;

        const int ml = m & 63;            // lane part
        const int mk = (m >> 6) & 7;      // reg part
        const int mw = (m >> 9) & 7;      // wave part
        float pr[8], pim[8];
        if (mw == 0 && ml == 0) {
            #pragma unroll
            for (int k = 0; k < 8; ++k) { pr[k] = ar[k ^ mk]; pim[k] = ai[k ^ mk]; }
        } else if (mw == 0) {
            #pragma unroll
            for (int k = 0; k < 8; ++k) {
                pr[k]  = __shfl_xor(ar[k ^ mk], ml, 64);
                pim[k] = __shfl_xor(ai[k ^ mk], ml, 64);
            }
        } else {
            const int tm = (mw << 6) | ml;
            __syncthreads();   // WAR: prior readers of lds done
            #pragma unroll
            for (int k = 0; k < 8; ++k) {
                lds_r[k * 512 + tid] = ar[k];
                lds_i[k * 512 + tid] = ai[k];
            }
            __syncthreads();
            #pragma unroll
            for (int k = 0; k < 8; ++k) {
                pr[k]  = lds_r[(k ^ mk) * 512 + (tid ^ tm)];
                pim[k] = lds_i[(k ^ mk) * 512 + (tid ^ tm)];
            }
        }
        const int ku = (u >> 6) & 7;
        #pragma unroll
        for (int k = 0; k < 8; ++k) {
            const int cls = __popc(k & ku) & 1;   // compile-time per k
            const float Dr = cls ? D1r : D0r, Di = cls ? D1i : D0i;
            const float Or = cls ? O1r : O0r, Oi = cls ? O1i : O0i;
            float nr = Dr * ar[k] - Di * ai[k] + Or * pr[k] - Oi * pim[k];
            float ni = Dr * ai[k] + Di * ar[k] + Or * pim[k] + Oi * pr[k];
            ar[k] = nr; ai[k] = ni;
        }
    }
}

// ============ 5 segment kernels: 256 blocks x 512 threads, A = 8 ============
// h = p<<12 | w<<9 | k<<6 | l ;  e = blk>>2, p = blk&3, w = tid>>6, l = tid&63
// Boundary sigma ({12,13}<->{6,7}): writer amp (p,w,k,l) -> buffer slot
//   (k&3)<<12 | w<<9 | (k>>2)<<8 | p<<6 | l   (reader-linear; both sides coalesced)
// SEG 0: analytic product init (no gin). SEG 4: measurement + atomic head (no gout).
template<int SEG>
__global__ void __launch_bounds__(512)
qvc_seg(const float* __restrict__ x, const float2* __restrict__ gin,
        float2* __restrict__ gout, const float* __restrict__ W,
        const float* __restrict__ bias, float* __restrict__ out)
{
    __shared__ __align__(16) float uc[NCOEF][8];
    __shared__ float lds_r[8 * 512];
    __shared__ float lds_i[8 * 512];
    __shared__ float red[8][NQ];
    __shared__ float eqv[NQ];

    const int blk = blockIdx.x;
    const int e = blk >> 2, p = blk & 3;
    const int tid = threadIdx.x;
    const int w = tid >> 6, l = tid & 63;
    const int hbase = (p << 12) | (w << 9) | l;   // h minus the k bits
    const float* xb = x + e * NPAR;

    // ---- all 70 gate-coefficient sets, one per thread (init uses slots 0..13) ----
    if (tid < NCOEF) {
        const int layer = tid / 14, q = tid % 14;
        const int pidx = (layer < 4) ? layer * 42 + q * 3 : 168 + q * 2;
        float a1 = 0.5f * xb[pidx], a2 = 0.5f * xb[pidx + 1];
        float s1, c1, s2, c2;
        sincosf(a1, &s1, &c1);
        sincosf(a2, &s2, &c2);
        float A00r =  c2 * c1, A00i =  s2 * s1;
        float A01r = -s2 * c1, A01i = -c2 * s1;
        float A10r =  s2 * c1, A10i = -c2 * s1;
        float A11r =  c2 * c1, A11i = -s2 * s1;
        float U0, U1, U2, U3, U4, U5, U6, U7;
        if (layer < 4) {
            float a3 = 0.5f * xb[pidx + 2]; float s3, c3; sincosf(a3, &s3, &c3);
            U0 = c3 * A00r + s3 * A00i; U1 = c3 * A00i - s3 * A00r;
            U2 = c3 * A01r + s3 * A01i; U3 = c3 * A01i - s3 * A01r;
            U4 = c3 * A10r - s3 * A10i; U5 = c3 * A10i + s3 * A10r;
            U6 = c3 * A11r - s3 * A11i; U7 = c3 * A11i + s3 * A11r;
        } else {
            U0 = A00r; U1 = A00i; U2 = A01r; U3 = A01i;
            U4 = A10r; U5 = A10i; U6 = A11r; U7 = A11i;
        }
        uc[tid][0] = U0; uc[tid][1] = U1; uc[tid][2] = U2; uc[tid][3] = U3;
        uc[tid][4] = U4; uc[tid][5] = U5; uc[tid][6] = U6; uc[tid][7] = U7;
    }
    __syncthreads();

    float ar[8], ai[8];
    if constexpr (SEG == 0) {
        // analytic init: d[h] = prod_q U_q[bit_{13-q}(h^(h>>1))][0]  (verified r10)
        const int ghi = (hbase ^ (hbase >> 1)) >> 9;   // bits 13:9 (k-invariant)
        float br = 1.0f, bi = 0.0f;
        #pragma unroll
        for (int q = 0; q < 5; ++q) {                  // q=0..4 -> bp=13..9
            const int b = (ghi >> (4 - q)) & 1;
            const float fr = b ? uc[q][4] : uc[q][0];
            const float fi = b ? uc[q][5] : uc[q][1];
            const float nr = br * fr - bi * fi;
            const float ni = br * fi + bi * fr;
            br = nr; bi = ni;
        }
        #pragma unroll
        for (int k = 0; k < 8; ++k) {
            const int h  = hbase | (k << 6);
            const int gh = h ^ (h >> 1);
            float re = br, im = bi;
            #pragma unroll
            for (int q = 5; q < NQ; ++q) {             // bp = 13-q = 8..0
                const int b = (gh >> (13 - q)) & 1;
                const float fr = b ? uc[q][4] : uc[q][0];
                const float fi = b ? uc[q][5] : uc[q][1];
                const float nr = re * fr - im * fi;
                const float ni = re * fi + im * fr;
                re = nr; im = ni;
            }
            ar[k] = re; ai[k] = im;
        }
    } else {
        #pragma unroll
        for (int k = 0; k < 8; ++k) {
            float2 v = gin[(e << 14) | hbase | (k << 6)];
            ar[k] = v.x; ai[k] = v.y;
        }
    }

    do_gates<SEG>(ar, ai, uc, lds_r, lds_i, tid, hbase);

    if constexpr (SEG < 4) {
        #pragma unroll
        for (int k = 0; k < 8; ++k) {
            const int idx = (e << 14) | ((k & 3) << 12) | (w << 9) |
                            ((k >> 2) << 8) | (p << 6) | l;
            gout[idx] = make_float2(ar[k], ai[k]);
        }
    } else {
        // ---- measurement: E_q = sum |amp|^2 * (-1)^parity(h & mu[q]) ----
        float eq[NQ];
        #pragma unroll
        for (int q = 0; q < NQ; ++q) eq[q] = 0.0f;
        #pragma unroll
        for (int k = 0; k < 8; ++k) {
            float p2 = ar[k] * ar[k] + ai[k] * ai[k];
            #pragma unroll
            for (int q = 0; q < NQ; ++q) {
                if (__popc(k & ((TAB.mu[q] >> 6) & 7)) & 1) eq[q] -= p2; else eq[q] += p2;
            }
        }
        #pragma unroll
        for (int q = 0; q < NQ; ++q) {
            float v = (__popc(hbase & TAB.mu[q]) & 1) ? -eq[q] : eq[q];
            #pragma unroll
            for (int off = 32; off > 0; off >>= 1) v += __shfl_down(v, off, 64);
            eq[q] = v;
        }
        if (l == 0) {
            #pragma unroll
            for (int q = 0; q < NQ; ++q) red[w][q] = eq[q];
        }
        __syncthreads();
        if (tid < NQ) {
            float s = 0.0f;
            #pragma unroll
            for (int ww = 0; ww < 8; ++ww) s += red[ww][tid];
            eqv[tid] = s;
        }
        __syncthreads();
        // ---- head folded in: atomicAdd partial dot products (out pre-zeroed) ----
        if (tid < NCLS) {
            float acc = (p == 0) ? bias[tid] : 0.0f;
            #pragma unroll
            for (int q = 0; q < NQ; ++q) acc += W[tid * NQ + q] * eqv[q];
            atomicAdd(&out[e * NCLS + tid], acc);   // device-scope, cross-XCD safe
        }
    }
}

extern "C" void kernel_launch(void* const* d_in, const int* in_sizes, int n_in,
                              void* d_out, int out_size, void* d_ws, size_t ws_size,
                              hipStream_t stream)
{
    const float* x    = (const float*)d_in[0];   // (64, 196)
    const float* W    = (const float*)d_in[1];   // (10, 14)
    const float* bias = (const float*)d_in[2];   // (10,)
    float*       out  = (float*)d_out;           // (64, 10)

    const size_t state_elems = (size_t)64 * DIM;          // float2 each
    float2* bufA = (float2*)d_ws;
    float2* bufB = bufA + state_elems;
    (void)ws_size;  // observed 268 MB >> 16 MB needed

    // out accumulated via atomicAdd in seg<4>: zero it each call (graph memset node)
    hipMemsetAsync(out, 0, 64 * NCLS * sizeof(float), stream);

    hipLaunchKernelGGL(qvc_seg<0>, dim3(256), dim3(512), 0, stream,
                       x, (const float2*)nullptr, bufA, W, bias, out);
    hipLaunchKernelGGL(qvc_seg<1>, dim3(256), dim3(512), 0, stream,
                       x, bufA, bufB, W, bias, out);
    hipLaunchKernelGGL(qvc_seg<2>, dim3(256), dim3(512), 0, stream,
                       x, bufB, bufA, W, bias, out);
    hipLaunchKernelGGL(qvc_seg<3>, dim3(256), dim3(512), 0, stream,
                       x, bufA, bufB, W, bias, out);
    hipLaunchKernelGGL(qvc_seg<4>, dim3(256), dim3(512), 0, stream,
                       x, bufB, (float2*)nullptr, W, bias, out);
}

// Round 13
// 53.000 us; speedup vs baseline: 3.6939x; 1.2917x over previous
//
#include <hip/hip_runtime.h>

#define NQ     14
#define DIM    16384
#define NPAR   196
#define NCLS   10
#define NGT    42     // gate table: rounds 2..4 (rounds 0-1 + chains 0-1 in TT init)
#define NCOEF  70     // all 70 coefficient sets (init uses slots 0..27)

// ---------------- compile-time frame/gate tables ----------------
// Stored state d[h] = s_ref[A(h)], A linear over GF(2)^14.
//  - U0, C0, U1, C1 folded into the chi=2 tensor-train init (identity frame after):
//      d[h] = sum_j prod_bp V_bp[gh_bp, j_bp] * phi_bp[j_bp ^ j_{bp+1}],  gh=h^(h>>1)
//    (phi = column 0 of layer-0 gate, V = full layer-1 gate; j_14=0)
//  - CNOT chain:  m[bp]^=m[bp-1]; u = suffix-xor   (chains 2,3)
//  - rotation on ref bit bp: pair h <-> h^m[bp], role = parity(h & u[bp])
//  - physical relabel sigma (bits {12,13}<->{6,7}) => m,u <- sigma(m),sigma(u)
// Layout: h = p(2b,13:12) | w(3b,11:9) | k(3b,8:6) | lane(6b,5:0)
// 3 rounds (r=2..4): phase-1 gates (m avoids bits 12,13), sigma (inter-kernel
// exchange), phase-2 gates (local after sigma). 3 boundaries -> 4 kernels.
struct GateInfo { int m; int u; int slot; };
struct Tables { GateInfo g[NGT]; int mu[NQ]; int swap_at[3]; bool valid; };

constexpr unsigned swapbits(unsigned v) {   // swap bits {6,7} <-> {12,13}
    return (v & ~0x30C0u) | ((v & 0xC0u) << 6) | ((v >> 6) & 0xC0u);
}

constexpr Tables make_tables() {
    Tables T{};
    T.valid = true;
    unsigned m[NQ] = {}, u[NQ] = {};
    for (int i = 0; i < NQ; ++i) { m[i] = 1u << i; u[i] = 1u << i; }
    int gi = 0;
    for (int r = 2; r <= 4; ++r) {
        bool done[NQ] = {};
        for (int q = 0; q < NQ; ++q) {            // phase 1: m avoids bits 12,13
            int bp = 13 - q;
            if ((m[bp] & 0x3000u) == 0u) {
                T.g[gi].m = (int)m[bp]; T.g[gi].u = (int)u[bp];
                T.g[gi].slot = r * 14 + q;
                done[q] = true; ++gi;
            }
        }
        T.swap_at[r - 2] = gi;
        if (r > 2 && T.swap_at[r - 2] <= T.swap_at[r - 3]) T.valid = false;
        for (int i = 0; i < NQ; ++i) { m[i] = swapbits(m[i]); u[i] = swapbits(u[i]); }
        for (int q = 0; q < NQ; ++q) {            // phase 2: local after sigma
            if (!done[q]) {
                int bp = 13 - q;
                if ((m[bp] & 0x3000u) != 0u) T.valid = false;
                T.g[gi].m = (int)m[bp]; T.g[gi].u = (int)u[bp];
                T.g[gi].slot = r * 14 + q;
                ++gi;
            }
        }
        if (r < 4) {                              // chains 2,3 retabulation
            for (int bp = 13; bp >= 1; --bp) m[bp] ^= m[bp - 1];
            unsigned acc = 0;
            for (int bp = 13; bp >= 0; --bp) { acc ^= u[bp]; u[bp] = acc; }
        }
    }
    if (gi != NGT) T.valid = false;
    for (int q = 0; q < NQ; ++q) T.mu[q] = (int)u[13 - q];
    return T;
}
constexpr Tables TAB = make_tables();
static_assert(TAB.valid, "gate schedule construction failed");
static_assert(TAB.swap_at[0] > 0 && TAB.swap_at[2] < NGT, "segment layout");

constexpr int seg_lo(int s) { return s == 0 ? 0 : TAB.swap_at[s - 1]; }
constexpr int seg_hi(int s) { return s < 3 ? TAB.swap_at[s] : NGT; }

// ---- chi=2 tensor-train step helpers (site bp: V=layer-1 gate, phi=layer-0 col0)
// R'[c] = sum_b V[ghb][b] * phi[b^c] * R[b]
__device__ __forceinline__ void tt_step(float& r0r, float& r0i, float& r1r, float& r1i,
                                        const float* Vu, const float* Pu, int ghb)
{
    const float v0r = Vu[ghb * 4 + 0], v0i = Vu[ghb * 4 + 1];
    const float v1r = Vu[ghb * 4 + 2], v1i = Vu[ghb * 4 + 3];
    const float Ar = v0r * r0r - v0i * r0i, Ai = v0r * r0i + v0i * r0r;
    const float Br = v1r * r1r - v1i * r1i, Bi = v1r * r1i + v1i * r1r;
    const float p0r = Pu[0], p0i = Pu[1], p1r = Pu[4], p1i = Pu[5];
    r0r = Ar * p0r - Ai * p0i + Br * p1r - Bi * p1i;
    r0i = Ar * p0i + Ai * p0r + Br * p1i + Bi * p1r;
    r1r = Ar * p1r - Ai * p1i + Br * p0r - Bi * p0i;
    r1i = Ar * p1i + Ai * p1r + Br * p0i + Bi * p0r;
}
// W'[j] = V[ghb][j] * (phi[j]*W0 + phi[j^1]*W1)
__device__ __forceinline__ void tt_wstep(float& w0r, float& w0i, float& w1r, float& w1i,
                                         const float* Vu, const float* Pu, int ghb)
{
    const float p0r = Pu[0], p0i = Pu[1], p1r = Pu[4], p1i = Pu[5];
    const float t0r = p0r * w0r - p0i * w0i + p1r * w1r - p1i * w1i;
    const float t0i = p0r * w0i + p0i * w0r + p1r * w1i + p1i * w1r;
    const float t1r = p1r * w0r - p1i * w0i + p0r * w1r - p0i * w1i;
    const float t1i = p1r * w0i + p1i * w0r + p0r * w1i + p0i * w1r;
    const float v0r = Vu[ghb * 4 + 0], v0i = Vu[ghb * 4 + 1];
    const float v1r = Vu[ghb * 4 + 2], v1i = Vu[ghb * 4 + 3];
    w0r = v0r * t0r - v0i * t0i; w0i = v0r * t0i + v0i * t0r;
    w1r = v1r * t1r - v1i * t1i; w1i = v1r * t1i + v1i * t1r;
}

// Apply gates [seg_lo(SEG), seg_hi(SEG)) to the 8 register amps.
template<int SEG>
__device__ __forceinline__ void do_gates(float (&ar)[8], float (&ai)[8],
    const float (*uc)[8], float* lds_r, float* lds_i, int tid, int hbase)
{
    constexpr int LO = seg_lo(SEG);
    constexpr int HI = seg_hi(SEG);
    #pragma unroll
    for (int g = LO; g < HI; ++g) {
        const int m = TAB.g[g].m, u = TAB.g[g].u;
        const float4 c0 = *(const float4*)&uc[TAB.g[g].slot][0];  // {00r,00i,01r,01i}
        const float4 c1 = *(const float4*)&uc[TAB.g[g].slot][4];  // {10r,10i,11r,11i}
        const bool rb = (__popc(hbase & u) & 1) != 0;
        const float D0r = rb ? c1.z : c0.x, D0i = rb ? c1.w : c0.y;
        const float O0r = rb ? c1.x : c0.z, O0i = rb ? c1.y : c0.w;
        const float D1r = rb ? c0.x : c1.z, D1i = rb ? c0.y : c1.w;
        const float O1r = rb ? c0.z : c1.x, O1i = rb ? c0.w : c1.y;

        const int ml = m & 63;            // lane part
        const int mk = (m >> 6) & 7;      // reg part
        const int mw = (m >> 9) & 7;      // wave part
        float pr[8], pim[8];
        if (mw == 0 && ml == 0) {
            #pragma unroll
            for (int k = 0; k < 8; ++k) { pr[k] = ar[k ^ mk]; pim[k] = ai[k ^ mk]; }
        } else if (mw == 0) {
            #pragma unroll
            for (int k = 0; k < 8; ++k) {
                pr[k]  = __shfl_xor(ar[k ^ mk], ml, 64);
                pim[k] = __shfl_xor(ai[k ^ mk], ml, 64);
            }
        } else {
            const int tm = (mw << 6) | ml;
            __syncthreads();   // WAR: prior readers of lds done
            #pragma unroll
            for (int k = 0; k < 8; ++k) {
                lds_r[k * 512 + tid] = ar[k];
                lds_i[k * 512 + tid] = ai[k];
            }
            __syncthreads();
            #pragma unroll
            for (int k = 0; k < 8; ++k) {
                pr[k]  = lds_r[(k ^ mk) * 512 + (tid ^ tm)];
                pim[k] = lds_i[(k ^ mk) * 512 + (tid ^ tm)];
            }
        }
        const int ku = (u >> 6) & 7;
        #pragma unroll
        for (int k = 0; k < 8; ++k) {
            const int cls = __popc(k & ku) & 1;   // compile-time per k
            const float Dr = cls ? D1r : D0r, Di = cls ? D1i : D0i;
            const float Or = cls ? O1r : O0r, Oi = cls ? O1i : O0i;
            float nr = Dr * ar[k] - Di * ai[k] + Or * pr[k] - Oi * pim[k];
            float ni = Dr * ai[k] + Di * ar[k] + Or * pim[k] + Oi * pr[k];
            ar[k] = nr; ai[k] = ni;
        }
    }
}

// ============ 4 segment kernels: 256 blocks x 512 threads, A = 8 ============
// h = p<<12 | w<<9 | k<<6 | l ;  e = blk>>2, p = blk&3, w = tid>>6, l = tid&63
// Boundary sigma ({12,13}<->{6,7}): writer amp (p,w,k,l) -> buffer slot
//   (k&3)<<12 | w<<9 | (k>>2)<<8 | p<<6 | l   (reader-linear; both sides coalesced)
// SEG 0: chi=2 TT init (no gin). SEG 1: zeroes out. SEG 3: measure + atomic head.
template<int SEG>
__global__ void __launch_bounds__(512)
qvc_seg(const float* __restrict__ x, const float2* __restrict__ gin,
        float2* __restrict__ gout, const float* __restrict__ W,
        const float* __restrict__ bias, float* __restrict__ out)
{
    __shared__ __align__(16) float uc[NCOEF][8];
    __shared__ float lds_r[8 * 512];
    __shared__ float lds_i[8 * 512];
    __shared__ float red[8][NQ];
    __shared__ float eqv[NQ];

    const int blk = blockIdx.x;
    const int e = blk >> 2, p = blk & 3;
    const int tid = threadIdx.x;
    const int w = tid >> 6, l = tid & 63;
    const int hbase = (p << 12) | (w << 9) | l;   // h minus the k bits
    const float* xb = x + e * NPAR;

    if constexpr (SEG == 1) {           // fold the out-zeroing (replaces memset node)
        if (blk == 0)
            for (int t = tid; t < 64 * NCLS; t += 512) out[t] = 0.0f;
    }

    // ---- all 70 gate-coefficient sets, one per thread ----
    if (tid < NCOEF) {
        const int layer = tid / 14, q = tid % 14;
        const int pidx = (layer < 4) ? layer * 42 + q * 3 : 168 + q * 2;
        float a1 = 0.5f * xb[pidx], a2 = 0.5f * xb[pidx + 1];
        float s1, c1, s2, c2;
        sincosf(a1, &s1, &c1);
        sincosf(a2, &s2, &c2);
        float A00r =  c2 * c1, A00i =  s2 * s1;
        float A01r = -s2 * c1, A01i = -c2 * s1;
        float A10r =  s2 * c1, A10i = -c2 * s1;
        float A11r =  c2 * c1, A11i = -s2 * s1;
        float U0, U1, U2, U3, U4, U5, U6, U7;
        if (layer < 4) {
            float a3 = 0.5f * xb[pidx + 2]; float s3, c3; sincosf(a3, &s3, &c3);
            U0 = c3 * A00r + s3 * A00i; U1 = c3 * A00i - s3 * A00r;
            U2 = c3 * A01r + s3 * A01i; U3 = c3 * A01i - s3 * A01r;
            U4 = c3 * A10r - s3 * A10i; U5 = c3 * A10i + s3 * A10r;
            U6 = c3 * A11r - s3 * A11i; U7 = c3 * A11i + s3 * A11r;
        } else {
            U0 = A00r; U1 = A00i; U2 = A01r; U3 = A01i;
            U4 = A10r; U5 = A10i; U6 = A11r; U7 = A11i;
        }
        uc[tid][0] = U0; uc[tid][1] = U1; uc[tid][2] = U2; uc[tid][3] = U3;
        uc[tid][4] = U4; uc[tid][5] = U5; uc[tid][6] = U6; uc[tid][7] = U7;
    }
    __syncthreads();

    float ar[8], ai[8];
    if constexpr (SEG == 0) {
        // ---- chi=2 TT init: d[h] = state after C1*U1*C0*U0|0>, identity frame ----
        // site bp: q=13-bp; phi = uc[q] (col 0), V = uc[14+q] (full 2x2)
        const int ghs = hbase ^ (hbase >> 1);     // bits 0..4 and 9..13 valid (k-indep)
        // R after sites 0..4 (shared across k); R starts as (1,1)
        float R0r = 1.0f, R0i = 0.0f, R1r = 1.0f, R1i = 0.0f;
        #pragma unroll
        for (int bp = 0; bp < 5; ++bp)
            tt_step(R0r, R0i, R1r, R1i, &uc[14 + (13 - bp)][0], &uc[13 - bp][0],
                    (ghs >> bp) & 1);
        // W from sites 13 down to 9 (shared): base site 13 (j_14 = 0)
        float W0r, W0i, W1r, W1i;
        {
            const int b13 = (ghs >> 13) & 1;
            const float* Vu = &uc[14 + 0][0];     // q = 13-13 = 0
            const float* Pu = &uc[0][0];
            // W[j] = V[b13][j] * phi[j]
            const float v0r = Vu[b13 * 4 + 0], v0i = Vu[b13 * 4 + 1];
            const float v1r = Vu[b13 * 4 + 2], v1i = Vu[b13 * 4 + 3];
            W0r = v0r * Pu[0] - v0i * Pu[1]; W0i = v0r * Pu[1] + v0i * Pu[0];
            W1r = v1r * Pu[4] - v1i * Pu[5]; W1i = v1r * Pu[5] + v1i * Pu[4];
        }
        #pragma unroll
        for (int bp = 12; bp >= 9; --bp)
            tt_wstep(W0r, W0i, W1r, W1i, &uc[14 + (13 - bp)][0], &uc[13 - bp][0],
                     (ghs >> bp) & 1);
        // per-k middle: sites 5..8, then d = R.W
        #pragma unroll
        for (int k = 0; k < 8; ++k) {
            const int hh = hbase | (k << 6);
            const int ghk = hh ^ (hh >> 1);
            float r0r = R0r, r0i = R0i, r1r = R1r, r1i = R1i;
            #pragma unroll
            for (int bp = 5; bp <= 8; ++bp)
                tt_step(r0r, r0i, r1r, r1i, &uc[14 + (13 - bp)][0], &uc[13 - bp][0],
                        (ghk >> bp) & 1);
            ar[k] = r0r * W0r - r0i * W0i + r1r * W1r - r1i * W1i;
            ai[k] = r0r * W0i + r0i * W0r + r1r * W1i + r1i * W1r;
        }
    } else {
        #pragma unroll
        for (int k = 0; k < 8; ++k) {
            float2 v = gin[(e << 14) | hbase | (k << 6)];
            ar[k] = v.x; ai[k] = v.y;
        }
    }

    do_gates<SEG>(ar, ai, uc, lds_r, lds_i, tid, hbase);

    if constexpr (SEG < 3) {
        #pragma unroll
        for (int k = 0; k < 8; ++k) {
            const int idx = (e << 14) | ((k & 3) << 12) | (w << 9) |
                            ((k >> 2) << 8) | (p << 6) | l;
            gout[idx] = make_float2(ar[k], ai[k]);
        }
    } else {
        // ---- measurement: E_q = sum |amp|^2 * (-1)^parity(h & mu[q]) ----
        float eq[NQ];
        #pragma unroll
        for (int q = 0; q < NQ; ++q) eq[q] = 0.0f;
        #pragma unroll
        for (int k = 0; k < 8; ++k) {
            float p2 = ar[k] * ar[k] + ai[k] * ai[k];
            #pragma unroll
            for (int q = 0; q < NQ; ++q) {
                if (__popc(k & ((TAB.mu[q] >> 6) & 7)) & 1) eq[q] -= p2; else eq[q] += p2;
            }
        }
        #pragma unroll
        for (int q = 0; q < NQ; ++q) {
            float v = (__popc(hbase & TAB.mu[q]) & 1) ? -eq[q] : eq[q];
            #pragma unroll
            for (int off = 32; off > 0; off >>= 1) v += __shfl_down(v, off, 64);
            eq[q] = v;
        }
        if (l == 0) {
            #pragma unroll
            for (int q = 0; q < NQ; ++q) red[w][q] = eq[q];
        }
        __syncthreads();
        if (tid < NQ) {
            float s = 0.0f;
            #pragma unroll
            for (int ww = 0; ww < 8; ++ww) s += red[ww][tid];
            eqv[tid] = s;
        }
        __syncthreads();
        // ---- head folded in: atomicAdd partial dot products (out zeroed in SEG 1) ----
        if (tid < NCLS) {
            float acc = (p == 0) ? bias[tid] : 0.0f;
            #pragma unroll
            for (int q = 0; q < NQ; ++q) acc += W[tid * NQ + q] * eqv[q];
            atomicAdd(&out[e * NCLS + tid], acc);   // device-scope, cross-XCD safe
        }
    }
}

extern "C" void kernel_launch(void* const* d_in, const int* in_sizes, int n_in,
                              void* d_out, int out_size, void* d_ws, size_t ws_size,
                              hipStream_t stream)
{
    const float* x    = (const float*)d_in[0];   // (64, 196)
    const float* W    = (const float*)d_in[1];   // (10, 14)
    const float* bias = (const float*)d_in[2];   // (10,)
    float*       out  = (float*)d_out;           // (64, 10)

    const size_t state_elems = (size_t)64 * DIM;          // float2 each
    float2* bufA = (float2*)d_ws;
    float2* bufB = bufA + state_elems;
    (void)ws_size;  // observed 268 MB >> 16 MB needed

    hipLaunchKernelGGL(qvc_seg<0>, dim3(256), dim3(512), 0, stream,
                       x, (const float2*)nullptr, bufA, W, bias, out);
    hipLaunchKernelGGL(qvc_seg<1>, dim3(256), dim3(512), 0, stream,
                       x, bufA, bufB, W, bias, out);
    hipLaunchKernelGGL(qvc_seg<2>, dim3(256), dim3(512), 0, stream,
                       x, bufB, bufA, W, bias, out);
    hipLaunchKernelGGL(qvc_seg<3>, dim3(256), dim3(512), 0, stream,
                       x, bufA, (float2*)nullptr, W, bias, out);
}

// Round 14
// 49.044 us; speedup vs baseline: 3.9918x; 1.0807x over previous
//
#include <hip/hip_runtime.h>

#define NQ     14
#define DIM    16384
#define NPAR   196
#define NCLS   10
#define NGT    28     // gate table: rounds 3..4 (layers 0-2 + chains 0-2 in TT init)
#define NCOEF  70     // all 70 coefficient sets (init uses slots 0..41)

// ---------------- compile-time frame/gate tables ----------------
// Stored state d[h] = s_ref[A(h)], A linear over GF(2)^14.
//  - U0,C0,U1,C1,U2,C2 folded into the chi=4 tensor-train init (identity frame
//    after): d[h] = sum_{j2,j} prod_bp V2[gh_bp,j2_bp] V1[j2_bp^j2_{bp+1}, j_bp]
//                               * phi[j_bp^j_{bp+1}],   gh = h^(h>>1)
//    (phi = col 0 of layer-0 gate, V1 = layer-1 gate, V2 = layer-2 gate; j*_14=0)
//  - CNOT chain:  m[bp]^=m[bp-1]; u = suffix-xor   (chain 3)
//  - rotation on ref bit bp: pair h <-> h^m[bp], role = parity(h & u[bp])
//  - physical relabel sigma (bits {12,13}<->{6,7}) => m,u <- sigma(m),sigma(u)
// Layout: h = p(2b,13:12) | w(3b,11:9) | k(3b,8:6) | lane(6b,5:0)
// 2 rounds (r=3,4): phase-1 gates (m avoids bits 12,13), sigma (inter-kernel
// exchange), phase-2 gates (local after sigma). 2 boundaries -> 3 kernels.
struct GateInfo { int m; int u; int slot; };
struct Tables { GateInfo g[NGT]; int mu[NQ]; int swap_at[2]; bool valid; };

constexpr unsigned swapbits(unsigned v) {   // swap bits {6,7} <-> {12,13}
    return (v & ~0x30C0u) | ((v & 0xC0u) << 6) | ((v >> 6) & 0xC0u);
}

constexpr Tables make_tables() {
    Tables T{};
    T.valid = true;
    unsigned m[NQ] = {}, u[NQ] = {};
    for (int i = 0; i < NQ; ++i) { m[i] = 1u << i; u[i] = 1u << i; }
    int gi = 0;
    for (int r = 3; r <= 4; ++r) {
        bool done[NQ] = {};
        for (int q = 0; q < NQ; ++q) {            // phase 1: m avoids bits 12,13
            int bp = 13 - q;
            if ((m[bp] & 0x3000u) == 0u) {
                T.g[gi].m = (int)m[bp]; T.g[gi].u = (int)u[bp];
                T.g[gi].slot = r * 14 + q;
                done[q] = true; ++gi;
            }
        }
        T.swap_at[r - 3] = gi;
        if (r > 3 && T.swap_at[r - 3] <= T.swap_at[r - 4]) T.valid = false;
        for (int i = 0; i < NQ; ++i) { m[i] = swapbits(m[i]); u[i] = swapbits(u[i]); }
        for (int q = 0; q < NQ; ++q) {            // phase 2: local after sigma
            if (!done[q]) {
                int bp = 13 - q;
                if ((m[bp] & 0x3000u) != 0u) T.valid = false;
                T.g[gi].m = (int)m[bp]; T.g[gi].u = (int)u[bp];
                T.g[gi].slot = r * 14 + q;
                ++gi;
            }
        }
        if (r < 4) {                              // chain 3 retabulation
            for (int bp = 13; bp >= 1; --bp) m[bp] ^= m[bp - 1];
            unsigned acc = 0;
            for (int bp = 13; bp >= 0; --bp) { acc ^= u[bp]; u[bp] = acc; }
        }
    }
    if (gi != NGT) T.valid = false;
    for (int q = 0; q < NQ; ++q) T.mu[q] = (int)u[13 - q];
    return T;
}
constexpr Tables TAB = make_tables();
static_assert(TAB.valid, "gate schedule construction failed");
static_assert(TAB.swap_at[0] > 0 && TAB.swap_at[1] > TAB.swap_at[0] &&
              TAB.swap_at[1] < NGT, "segment layout");

constexpr int seg_lo(int s) { return s == 0 ? 0 : TAB.swap_at[s - 1]; }
constexpr int seg_hi(int s) { return s < 2 ? TAB.swap_at[s] : NGT; }

// ---- chi=4 TT step (site bp). R index = c2*2+c, bond (j2_bp, j_bp).
// R'[c2',c'] = sum_{c2,c} V2[ghb,c2] * V1[c2^c2', c] * phi[c^c'] * R[c2,c]
__device__ __forceinline__ void tt4_step(float (&Rr)[4], float (&Ri)[4],
    const float* V2u, const float* V1u, const float* Pu, int ghb)
{
    float Ar[4], Ai[4];
    #pragma unroll
    for (int c2 = 0; c2 < 2; ++c2) {
        const float vr = V2u[ghb * 4 + c2 * 2], vi = V2u[ghb * 4 + c2 * 2 + 1];
        #pragma unroll
        for (int c = 0; c < 2; ++c) {
            const int j = c2 * 2 + c;
            Ar[j] = vr * Rr[j] - vi * Ri[j];
            Ai[j] = vr * Ri[j] + vi * Rr[j];
        }
    }
    float Br[4], Bi[4];
    #pragma unroll
    for (int c2p = 0; c2p < 2; ++c2p)
        #pragma unroll
        for (int c = 0; c < 2; ++c) {
            float sr = 0.0f, si = 0.0f;
            #pragma unroll
            for (int c2 = 0; c2 < 2; ++c2) {
                const float vr = V1u[(c2 ^ c2p) * 4 + c * 2];
                const float vi = V1u[(c2 ^ c2p) * 4 + c * 2 + 1];
                sr += vr * Ar[c2 * 2 + c] - vi * Ai[c2 * 2 + c];
                si += vr * Ai[c2 * 2 + c] + vi * Ar[c2 * 2 + c];
            }
            Br[c2p * 2 + c] = sr; Bi[c2p * 2 + c] = si;
        }
    #pragma unroll
    for (int c2p = 0; c2p < 2; ++c2p)
        #pragma unroll
        for (int cp = 0; cp < 2; ++cp) {
            float sr = 0.0f, si = 0.0f;
            #pragma unroll
            for (int c = 0; c < 2; ++c) {
                const float pr = Pu[(c ^ cp) * 4], pi = Pu[(c ^ cp) * 4 + 1];
                sr += pr * Br[c2p * 2 + c] - pi * Bi[c2p * 2 + c];
                si += pr * Bi[c2p * 2 + c] + pi * Br[c2p * 2 + c];
            }
            Rr[c2p * 2 + cp] = sr; Ri[c2p * 2 + cp] = si;
        }
}
// Suffix: W'[c2,c] = V2[ghb,c2] * sum_{c2',c'} V1[c2^c2',c] phi[c^c'] W[c2',c']
__device__ __forceinline__ void tt4_wstep(float (&Wr)[4], float (&Wi)[4],
    const float* V2u, const float* V1u, const float* Pu, int ghb)
{
    float Sr[4], Si[4];
    #pragma unroll
    for (int c2p = 0; c2p < 2; ++c2p)
        #pragma unroll
        for (int c = 0; c < 2; ++c) {
            float sr = 0.0f, si = 0.0f;
            #pragma unroll
            for (int cp = 0; cp < 2; ++cp) {
                const float pr = Pu[(c ^ cp) * 4], pi = Pu[(c ^ cp) * 4 + 1];
                sr += pr * Wr[c2p * 2 + cp] - pi * Wi[c2p * 2 + cp];
                si += pr * Wi[c2p * 2 + cp] + pi * Wr[c2p * 2 + cp];
            }
            Sr[c2p * 2 + c] = sr; Si[c2p * 2 + c] = si;
        }
    float Tr[4], Ti[4];
    #pragma unroll
    for (int c2 = 0; c2 < 2; ++c2)
        #pragma unroll
        for (int c = 0; c < 2; ++c) {
            float sr = 0.0f, si = 0.0f;
            #pragma unroll
            for (int c2p = 0; c2p < 2; ++c2p) {
                const float vr = V1u[(c2 ^ c2p) * 4 + c * 2];
                const float vi = V1u[(c2 ^ c2p) * 4 + c * 2 + 1];
                sr += vr * Sr[c2p * 2 + c] - vi * Si[c2p * 2 + c];
                si += vr * Si[c2p * 2 + c] + vi * Sr[c2p * 2 + c];
            }
            Tr[c2 * 2 + c] = sr; Ti[c2 * 2 + c] = si;
        }
    #pragma unroll
    for (int c2 = 0; c2 < 2; ++c2) {
        const float vr = V2u[ghb * 4 + c2 * 2], vi = V2u[ghb * 4 + c2 * 2 + 1];
        #pragma unroll
        for (int c = 0; c < 2; ++c) {
            const int j = c2 * 2 + c;
            Wr[j] = vr * Tr[j] - vi * Ti[j];
            Wi[j] = vr * Ti[j] + vi * Tr[j];
        }
    }
}

// Apply gates [seg_lo(SEG), seg_hi(SEG)) to the 8 register amps.
template<int SEG>
__device__ __forceinline__ void do_gates(float (&ar)[8], float (&ai)[8],
    const float (*uc)[8], float* lds_r, float* lds_i, int tid, int hbase)
{
    constexpr int LO = seg_lo(SEG);
    constexpr int HI = seg_hi(SEG);
    #pragma unroll
    for (int g = LO; g < HI; ++g) {
        const int m = TAB.g[g].m, u = TAB.g[g].u;
        const float4 c0 = *(const float4*)&uc[TAB.g[g].slot][0];  // {00r,00i,01r,01i}
        const float4 c1 = *(const float4*)&uc[TAB.g[g].slot][4];  // {10r,10i,11r,11i}
        const bool rb = (__popc(hbase & u) & 1) != 0;
        const float D0r = rb ? c1.z : c0.x, D0i = rb ? c1.w : c0.y;
        const float O0r = rb ? c1.x : c0.z, O0i = rb ? c1.y : c0.w;
        const float D1r = rb ? c0.x : c1.z, D1i = rb ? c0.y : c1.w;
        const float O1r = rb ? c0.z : c1.x, O1i = rb ? c0.w : c1.y;

        const int ml = m & 63;            // lane part
        const int mk = (m >> 6) & 7;      // reg part
        const int mw = (m >> 9) & 7;      // wave part
        float pr[8], pim[8];
        if (mw == 0 && ml == 0) {
            #pragma unroll
            for (int k = 0; k < 8; ++k) { pr[k] = ar[k ^ mk]; pim[k] = ai[k ^ mk]; }
        } else if (mw == 0) {
            #pragma unroll
            for (int k = 0; k < 8; ++k) {
                pr[k]  = __shfl_xor(ar[k ^ mk], ml, 64);
                pim[k] = __shfl_xor(ai[k ^ mk], ml, 64);
            }
        } else {
            const int tm = (mw << 6) | ml;
            __syncthreads();   // WAR: prior readers of lds done
            #pragma unroll
            for (int k = 0; k < 8; ++k) {
                lds_r[k * 512 + tid] = ar[k];
                lds_i[k * 512 + tid] = ai[k];
            }
            __syncthreads();
            #pragma unroll
            for (int k = 0; k < 8; ++k) {
                pr[k]  = lds_r[(k ^ mk) * 512 + (tid ^ tm)];
                pim[k] = lds_i[(k ^ mk) * 512 + (tid ^ tm)];
            }
        }
        const int ku = (u >> 6) & 7;
        #pragma unroll
        for (int k = 0; k < 8; ++k) {
            const int cls = __popc(k & ku) & 1;   // compile-time per k
            const float Dr = cls ? D1r : D0r, Di = cls ? D1i : D0i;
            const float Or = cls ? O1r : O0r, Oi = cls ? O1i : O0i;
            float nr = Dr * ar[k] - Di * ai[k] + Or * pr[k] - Oi * pim[k];
            float ni = Dr * ai[k] + Di * ar[k] + Or * pim[k] + Oi * pr[k];
            ar[k] = nr; ai[k] = ni;
        }
    }
}

// ============ 3 segment kernels: 256 blocks x 512 threads, A = 8 ============
// h = p<<12 | w<<9 | k<<6 | l ;  e = blk>>2, p = blk&3, w = tid>>6, l = tid&63
// Boundary sigma ({12,13}<->{6,7}): writer amp (p,w,k,l) -> buffer slot
//   (k&3)<<12 | w<<9 | (k>>2)<<8 | p<<6 | l   (reader-linear; both sides coalesced)
// SEG 0: chi=4 TT init (no gin). SEG 1: zeroes out. SEG 2: measure + atomic head.
template<int SEG>
__global__ void __launch_bounds__(512)
qvc_seg(const float* __restrict__ x, const float2* __restrict__ gin,
        float2* __restrict__ gout, const float* __restrict__ W,
        const float* __restrict__ bias, float* __restrict__ out)
{
    __shared__ __align__(16) float uc[NCOEF][8];
    __shared__ float lds_r[8 * 512];
    __shared__ float lds_i[8 * 512];
    __shared__ float red[8][NQ];
    __shared__ float eqv[NQ];

    const int blk = blockIdx.x;
    const int e = blk >> 2, p = blk & 3;
    const int tid = threadIdx.x;
    const int w = tid >> 6, l = tid & 63;
    const int hbase = (p << 12) | (w << 9) | l;   // h minus the k bits
    const float* xb = x + e * NPAR;

    if constexpr (SEG == 1) {           // fold the out-zeroing (replaces memset node)
        if (blk == 0)
            for (int t = tid; t < 64 * NCLS; t += 512) out[t] = 0.0f;
    }

    // ---- all 70 gate-coefficient sets, one per thread ----
    if (tid < NCOEF) {
        const int layer = tid / 14, q = tid % 14;
        const int pidx = (layer < 4) ? layer * 42 + q * 3 : 168 + q * 2;
        float a1 = 0.5f * xb[pidx], a2 = 0.5f * xb[pidx + 1];
        float s1, c1, s2, c2;
        sincosf(a1, &s1, &c1);
        sincosf(a2, &s2, &c2);
        float A00r =  c2 * c1, A00i =  s2 * s1;
        float A01r = -s2 * c1, A01i = -c2 * s1;
        float A10r =  s2 * c1, A10i = -c2 * s1;
        float A11r =  c2 * c1, A11i = -s2 * s1;
        float U0, U1, U2, U3, U4, U5, U6, U7;
        if (layer < 4) {
            float a3 = 0.5f * xb[pidx + 2]; float s3, c3; sincosf(a3, &s3, &c3);
            U0 = c3 * A00r + s3 * A00i; U1 = c3 * A00i - s3 * A00r;
            U2 = c3 * A01r + s3 * A01i; U3 = c3 * A01i - s3 * A01r;
            U4 = c3 * A10r - s3 * A10i; U5 = c3 * A10i + s3 * A10r;
            U6 = c3 * A11r - s3 * A11i; U7 = c3 * A11i + s3 * A11r;
        } else {
            U0 = A00r; U1 = A00i; U2 = A01r; U3 = A01i;
            U4 = A10r; U5 = A10i; U6 = A11r; U7 = A11i;
        }
        uc[tid][0] = U0; uc[tid][1] = U1; uc[tid][2] = U2; uc[tid][3] = U3;
        uc[tid][4] = U4; uc[tid][5] = U5; uc[tid][6] = U6; uc[tid][7] = U7;
    }
    __syncthreads();

    float ar[8], ai[8];
    if constexpr (SEG == 0) {
        // ---- chi=4 TT init: d = C2*U2*C1*U1*C0*U0|0>, identity frame after ----
        // site bp: q=13-bp; phi = uc[q] col0, V1 = uc[14+q], V2 = uc[28+q]
        const int ghs = hbase ^ (hbase >> 1);     // bits 0..4, 9..13 valid (k-indep)
        float Rr[4], Ri[4];
        #pragma unroll
        for (int j = 0; j < 4; ++j) { Rr[j] = 1.0f; Ri[j] = 0.0f; }
        #pragma unroll
        for (int bp = 0; bp < 5; ++bp)
            tt4_step(Rr, Ri, &uc[28 + (13 - bp)][0], &uc[14 + (13 - bp)][0],
                     &uc[13 - bp][0], (ghs >> bp) & 1);
        // suffix base: site 13 (j2_14 = j_14 = 0): W[c2,c] = V2[b13,c2] V1[c2,c] phi[c]
        float Wr[4], Wi[4];
        {
            const int b13 = (ghs >> 13) & 1;
            const float* V2u = &uc[28][0];
            const float* V1u = &uc[14][0];
            const float* Pu  = &uc[0][0];
            #pragma unroll
            for (int c2 = 0; c2 < 2; ++c2) {
                const float v2r = V2u[b13 * 4 + c2 * 2], v2i = V2u[b13 * 4 + c2 * 2 + 1];
                #pragma unroll
                for (int c = 0; c < 2; ++c) {
                    const float v1r = V1u[c2 * 4 + c * 2], v1i = V1u[c2 * 4 + c * 2 + 1];
                    const float pr = Pu[c * 4], pi = Pu[c * 4 + 1];
                    const float tr = v1r * pr - v1i * pi, ti = v1r * pi + v1i * pr;
                    Wr[c2 * 2 + c] = v2r * tr - v2i * ti;
                    Wi[c2 * 2 + c] = v2r * ti + v2i * tr;
                }
            }
        }
        #pragma unroll
        for (int bp = 12; bp >= 9; --bp)
            tt4_wstep(Wr, Wi, &uc[28 + (13 - bp)][0], &uc[14 + (13 - bp)][0],
                      &uc[13 - bp][0], (ghs >> bp) & 1);
        // per-k middle: sites 5..8, then d = sum R.W
        #pragma unroll
        for (int k = 0; k < 8; ++k) {
            const int hh = hbase | (k << 6);
            const int ghk = hh ^ (hh >> 1);
            float rr[4], ri[4];
            #pragma unroll
            for (int j = 0; j < 4; ++j) { rr[j] = Rr[j]; ri[j] = Ri[j]; }
            #pragma unroll
            for (int bp = 5; bp <= 8; ++bp)
                tt4_step(rr, ri, &uc[28 + (13 - bp)][0], &uc[14 + (13 - bp)][0],
                         &uc[13 - bp][0], (ghk >> bp) & 1);
            float dr = 0.0f, di = 0.0f;
            #pragma unroll
            for (int j = 0; j < 4; ++j) {
                dr += rr[j] * Wr[j] - ri[j] * Wi[j];
                di += rr[j] * Wi[j] + ri[j] * Wr[j];
            }
            ar[k] = dr; ai[k] = di;
        }
    } else {
        #pragma unroll
        for (int k = 0; k < 8; ++k) {
            float2 v = gin[(e << 14) | hbase | (k << 6)];
            ar[k] = v.x; ai[k] = v.y;
        }
    }

    do_gates<SEG>(ar, ai, uc, lds_r, lds_i, tid, hbase);

    if constexpr (SEG < 2) {
        #pragma unroll
        for (int k = 0; k < 8; ++k) {
            const int idx = (e << 14) | ((k & 3) << 12) | (w << 9) |
                            ((k >> 2) << 8) | (p << 6) | l;
            gout[idx] = make_float2(ar[k], ai[k]);
        }
    } else {
        // ---- measurement: E_q = sum |amp|^2 * (-1)^parity(h & mu[q]) ----
        float eq[NQ];
        #pragma unroll
        for (int q = 0; q < NQ; ++q) eq[q] = 0.0f;
        #pragma unroll
        for (int k = 0; k < 8; ++k) {
            float p2 = ar[k] * ar[k] + ai[k] * ai[k];
            #pragma unroll
            for (int q = 0; q < NQ; ++q) {
                if (__popc(k & ((TAB.mu[q] >> 6) & 7)) & 1) eq[q] -= p2; else eq[q] += p2;
            }
        }
        #pragma unroll
        for (int q = 0; q < NQ; ++q) {
            float v = (__popc(hbase & TAB.mu[q]) & 1) ? -eq[q] : eq[q];
            #pragma unroll
            for (int off = 32; off > 0; off >>= 1) v += __shfl_down(v, off, 64);
            eq[q] = v;
        }
        if (l == 0) {
            #pragma unroll
            for (int q = 0; q < NQ; ++q) red[w][q] = eq[q];
        }
        __syncthreads();
        if (tid < NQ) {
            float s = 0.0f;
            #pragma unroll
            for (int ww = 0; ww < 8; ++ww) s += red[ww][tid];
            eqv[tid] = s;
        }
        __syncthreads();
        // ---- head folded in: atomicAdd partial dot products (out zeroed in SEG 1) ----
        if (tid < NCLS) {
            float acc = (p == 0) ? bias[tid] : 0.0f;
            #pragma unroll
            for (int q = 0; q < NQ; ++q) acc += W[tid * NQ + q] * eqv[q];
            atomicAdd(&out[e * NCLS + tid], acc);   // device-scope, cross-XCD safe
        }
    }
}

extern "C" void kernel_launch(void* const* d_in, const int* in_sizes, int n_in,
                              void* d_out, int out_size, void* d_ws, size_t ws_size,
                              hipStream_t stream)
{
    const float* x    = (const float*)d_in[0];   // (64, 196)
    const float* W    = (const float*)d_in[1];   // (10, 14)
    const float* bias = (const float*)d_in[2];   // (10,)
    float*       out  = (float*)d_out;           // (64, 10)

    const size_t state_elems = (size_t)64 * DIM;          // float2 each
    float2* bufA = (float2*)d_ws;
    float2* bufB = bufA + state_elems;
    (void)ws_size;  // observed 268 MB >> 16 MB needed

    hipLaunchKernelGGL(qvc_seg<0>, dim3(256), dim3(512), 0, stream,
                       x, (const float2*)nullptr, bufA, W, bias, out);
    hipLaunchKernelGGL(qvc_seg<1>, dim3(256), dim3(512), 0, stream,
                       x, bufA, bufB, W, bias, out);
    hipLaunchKernelGGL(qvc_seg<2>, dim3(256), dim3(512), 0, stream,
                       x, bufB, (float2*)nullptr, W, bias, out);
}

// Round 16
// 46.552 us; speedup vs baseline: 4.2056x; 1.0535x over previous
//
#include <hip/hip_runtime.h>

#define NQ     14
#define DIM    16384
#define NPAR   196
#define NCLS   10
#define NGT    28     // U3 (14) + U4 (14); layers 0-2 + chains 0-2 in TT init
#define PH1    23     // kernel-0 gates: U3[13..2] (12) + U4[13..3] (11)
#define NCOEF  70     // all 70 coefficient sets (init uses slots 0..41)

// ---------------- compile-time gate tables (no sigma: masks never transform) ----------------
// Stored state d[h] = s_ref[A(h)].  After the chi=4 TT init (verified r14), A = I.
// Remaining circuit: U3 (m3=u3=e_bp), chain C3 absorbed into frame (A=g^-1,
// g(i)=i^(i>>1)) giving U4 masks m4[j]=e_j^e_{j-1} (m4[0]=e0), u4[j]=e13^..^e_j,
// and measurement masks mu[q]=u4[13-q].
// Commutation (Pauli-frame): gates (mA,uA),(mB,uB) commute iff
// parity(mA&uB)==0 && parity(mB&uA)==0.  Hence U4[j] requires ALL U3[bp>=j-1]
// first (u4 contains e13,e12 => every U4 after U3[13],U3[12]) -- the r15 bug.
// Valid split (layout choice, not mask transform):
//  kernel 0 (p-bits {1,0}):  U3[13..2] then U4[13..3]  (23 gates, all local)
//  kernel 1 (p-bits {13,12}): U3[1],U3[0],U4[2],U4[1],U4[0] (masks in bits 0..2)
// Cross-phase pairs commute: U4[j>=3] vs U3[bp<=1]: bp >= j-1 impossible. OK.
struct GateInfo { int m; int u; int slot; };
struct Tables { GateInfo g[NGT]; int mu[NQ]; bool valid; };

constexpr Tables make_tables() {
    Tables T{};
    T.valid = true;
    int gi = 0;
    for (int bp = 13; bp >= 2; --bp) {           // phase 1: U3
        T.g[gi].m = 1 << bp; T.g[gi].u = 1 << bp;
        T.g[gi].slot = 42 + (13 - bp); ++gi;
    }
    for (int j = 13; j >= 3; --j) {              // phase 1: U4 (preds all done)
        T.g[gi].m = (1 << j) | (1 << (j - 1));
        T.g[gi].u = 0x3FFF & ~((1 << j) - 1);
        T.g[gi].slot = 56 + (13 - j); ++gi;
    }
    if (gi != PH1) T.valid = false;
    T.g[gi].m = 2; T.g[gi].u = 2;               T.g[gi].slot = 42 + 12; ++gi; // U3[1]
    T.g[gi].m = 1; T.g[gi].u = 1;               T.g[gi].slot = 42 + 13; ++gi; // U3[0]
    T.g[gi].m = 6; T.g[gi].u = 0x3FFF & ~3;     T.g[gi].slot = 56 + 11; ++gi; // U4[2]
    T.g[gi].m = 3; T.g[gi].u = 0x3FFF & ~1;     T.g[gi].slot = 56 + 12; ++gi; // U4[1]
    T.g[gi].m = 1; T.g[gi].u = 0x3FFF;          T.g[gi].slot = 56 + 13; ++gi; // U4[0]
    if (gi != NGT) T.valid = false;
    for (int i = 0; i < PH1; ++i)   if (T.g[i].m & 0x0003) T.valid = false;  // k0 p-bits
    for (int i = PH1; i < NGT; ++i) if (T.g[i].m & 0x3000) T.valid = false;  // k1 p-bits
    for (int q = 0; q < NQ; ++q) T.mu[q] = 0x3FFF & ~((1 << (13 - q)) - 1);
    return T;
}
constexpr Tables TAB = make_tables();
static_assert(TAB.valid, "gate schedule construction failed");

// ---- chi=4 TT step (site bp). R index = c2*2+c, bond (j2_bp, j_bp). (verified r14)
__device__ __forceinline__ void tt4_step(float (&Rr)[4], float (&Ri)[4],
    const float* V2u, const float* V1u, const float* Pu, int ghb)
{
    float Ar[4], Ai[4];
    #pragma unroll
    for (int c2 = 0; c2 < 2; ++c2) {
        const float vr = V2u[ghb * 4 + c2 * 2], vi = V2u[ghb * 4 + c2 * 2 + 1];
        #pragma unroll
        for (int c = 0; c < 2; ++c) {
            const int j = c2 * 2 + c;
            Ar[j] = vr * Rr[j] - vi * Ri[j];
            Ai[j] = vr * Ri[j] + vi * Rr[j];
        }
    }
    float Br[4], Bi[4];
    #pragma unroll
    for (int c2p = 0; c2p < 2; ++c2p)
        #pragma unroll
        for (int c = 0; c < 2; ++c) {
            float sr = 0.0f, si = 0.0f;
            #pragma unroll
            for (int c2 = 0; c2 < 2; ++c2) {
                const float vr = V1u[(c2 ^ c2p) * 4 + c * 2];
                const float vi = V1u[(c2 ^ c2p) * 4 + c * 2 + 1];
                sr += vr * Ar[c2 * 2 + c] - vi * Ai[c2 * 2 + c];
                si += vr * Ai[c2 * 2 + c] + vi * Ar[c2 * 2 + c];
            }
            Br[c2p * 2 + c] = sr; Bi[c2p * 2 + c] = si;
        }
    #pragma unroll
    for (int c2p = 0; c2p < 2; ++c2p)
        #pragma unroll
        for (int cp = 0; cp < 2; ++cp) {
            float sr = 0.0f, si = 0.0f;
            #pragma unroll
            for (int c = 0; c < 2; ++c) {
                const float pr = Pu[(c ^ cp) * 4], pi = Pu[(c ^ cp) * 4 + 1];
                sr += pr * Br[c2p * 2 + c] - pi * Bi[c2p * 2 + c];
                si += pr * Bi[c2p * 2 + c] + pi * Br[c2p * 2 + c];
            }
            Rr[c2p * 2 + cp] = sr; Ri[c2p * 2 + cp] = si;
        }
}
__device__ __forceinline__ void tt4_wstep(float (&Wr)[4], float (&Wi)[4],
    const float* V2u, const float* V1u, const float* Pu, int ghb)
{
    float Sr[4], Si[4];
    #pragma unroll
    for (int c2p = 0; c2p < 2; ++c2p)
        #pragma unroll
        for (int c = 0; c < 2; ++c) {
            float sr = 0.0f, si = 0.0f;
            #pragma unroll
            for (int cp = 0; cp < 2; ++cp) {
                const float pr = Pu[(c ^ cp) * 4], pi = Pu[(c ^ cp) * 4 + 1];
                sr += pr * Wr[c2p * 2 + cp] - pi * Wi[c2p * 2 + cp];
                si += pr * Wi[c2p * 2 + cp] + pi * Wr[c2p * 2 + cp];
            }
            Sr[c2p * 2 + c] = sr; Si[c2p * 2 + c] = si;
        }
    float Tr[4], Ti[4];
    #pragma unroll
    for (int c2 = 0; c2 < 2; ++c2)
        #pragma unroll
        for (int c = 0; c < 2; ++c) {
            float sr = 0.0f, si = 0.0f;
            #pragma unroll
            for (int c2p = 0; c2p < 2; ++c2p) {
                const float vr = V1u[(c2 ^ c2p) * 4 + c * 2];
                const float vi = V1u[(c2 ^ c2p) * 4 + c * 2 + 1];
                sr += vr * Sr[c2p * 2 + c] - vi * Si[c2p * 2 + c];
                si += vr * Si[c2p * 2 + c] + vi * Sr[c2p * 2 + c];
            }
            Tr[c2 * 2 + c] = sr; Ti[c2 * 2 + c] = si;
        }
    #pragma unroll
    for (int c2 = 0; c2 < 2; ++c2) {
        const float vr = V2u[ghb * 4 + c2 * 2], vi = V2u[ghb * 4 + c2 * 2 + 1];
        #pragma unroll
        for (int c = 0; c < 2; ++c) {
            const int j = c2 * 2 + c;
            Wr[j] = vr * Tr[j] - vi * Ti[j];
            Wi[j] = vr * Ti[j] + vi * Tr[j];
        }
    }
}

// Apply this kernel's gate range. Layout-dependent mask decomposition:
//  SEG 0: h = w<<11 | k<<8 | l<<2 | p     (p: blk&3 -> h bits 1,0)
//  SEG 1: h = p<<12 | w<<9 | k2<<8 | l<<2 | k1<<1 | k0
template<int SEG>
__device__ __forceinline__ void do_gates(float (&ar)[8], float (&ai)[8],
    const float (*uc)[8], float* lds_r, float* lds_i, int tid, int hbase)
{
    constexpr int LO = (SEG == 0) ? 0 : PH1;
    constexpr int HI = (SEG == 0) ? PH1 : NGT;
    #pragma unroll
    for (int g = LO; g < HI; ++g) {
        const int m = TAB.g[g].m, u = TAB.g[g].u;
        const int ml = (m >> 2) & 63;
        const int mk = (SEG == 0) ? ((m >> 8) & 7)
                                  : ((((m >> 8) & 1) << 2) | (m & 3));
        const int mw = (SEG == 0) ? ((m >> 11) & 7) : ((m >> 9) & 7);
        const int ku = (SEG == 0) ? ((u >> 8) & 7)
                                  : ((((u >> 8) & 1) << 2) | (u & 3));
        const float4 c0 = *(const float4*)&uc[TAB.g[g].slot][0];  // {00r,00i,01r,01i}
        const float4 c1 = *(const float4*)&uc[TAB.g[g].slot][4];  // {10r,10i,11r,11i}
        const bool rb = (__popc(hbase & u) & 1) != 0;
        const float D0r = rb ? c1.z : c0.x, D0i = rb ? c1.w : c0.y;
        const float O0r = rb ? c1.x : c0.z, O0i = rb ? c1.y : c0.w;
        const float D1r = rb ? c0.x : c1.z, D1i = rb ? c0.y : c1.w;
        const float O1r = rb ? c0.z : c1.x, O1i = rb ? c0.w : c1.y;

        float pr[8], pim[8];
        if (mw == 0 && ml == 0) {
            #pragma unroll
            for (int k = 0; k < 8; ++k) { pr[k] = ar[k ^ mk]; pim[k] = ai[k ^ mk]; }
        } else if (mw == 0) {
            #pragma unroll
            for (int k = 0; k < 8; ++k) {
                pr[k]  = __shfl_xor(ar[k ^ mk], ml, 64);
                pim[k] = __shfl_xor(ai[k ^ mk], ml, 64);
            }
        } else {
            const int tm = (mw << 6) | ml;
            __syncthreads();   // WAR: prior readers of lds done
            #pragma unroll
            for (int k = 0; k < 8; ++k) {
                lds_r[k * 512 + tid] = ar[k];
                lds_i[k * 512 + tid] = ai[k];
            }
            __syncthreads();
            #pragma unroll
            for (int k = 0; k < 8; ++k) {
                pr[k]  = lds_r[(k ^ mk) * 512 + (tid ^ tm)];
                pim[k] = lds_i[(k ^ mk) * 512 + (tid ^ tm)];
            }
        }
        #pragma unroll
        for (int k = 0; k < 8; ++k) {
            const int cls = __popc(k & ku) & 1;   // compile-time per k
            const float Dr = cls ? D1r : D0r, Di = cls ? D1i : D0i;
            const float Or = cls ? O1r : O0r, Oi = cls ? O1i : O0i;
            float nr = Dr * ar[k] - Di * ai[k] + Or * pr[k] - Oi * pim[k];
            float ni = Dr * ai[k] + Di * ar[k] + Or * pim[k] + Oi * pr[k];
            ar[k] = nr; ai[k] = ni;
        }
    }
}

// ============ 2 kernels: 256 blocks x 512 threads, A = 8 ============
// Buffer index b(h) = h{7..2} | h{13..8}<<6 | h{1,0}<<12  (+ e<<14):
//  k0 store (fixed w,k): b = l | ((w<<3)|k)<<6 | p<<12        -> unit stride in l
//  k1 load  (fixed w,k'): b = l | ((p<<4)|(w<<1)|(k>>2))<<6 | (k&3)<<12 -> unit stride
template<int SEG>
__global__ void __launch_bounds__(512)
qvc_seg(const float* __restrict__ x, const float2* __restrict__ gin,
        float2* __restrict__ gout, const float* __restrict__ W,
        const float* __restrict__ bias, float* __restrict__ out)
{
    __shared__ __align__(16) float uc[NCOEF][8];
    __shared__ float lds_r[SEG == 0 ? 8 * 512 : 64];
    __shared__ float lds_i[SEG == 0 ? 8 * 512 : 64];
    __shared__ float red[8][NQ];
    __shared__ float eqv[NQ];

    const int blk = blockIdx.x;
    const int e = blk >> 2, p = blk & 3;
    const int tid = threadIdx.x;
    const int w = tid >> 6, l = tid & 63;
    const int hbase = (SEG == 0) ? ((w << 11) | (l << 2) | p)      // k bits 8..10 zero
                                 : ((p << 12) | (w << 9) | (l << 2)); // k' bits 8,1,0 zero
    const float* xb = x + e * NPAR;

    if constexpr (SEG == 0) {           // zero out before SEG1's atomics (stream order)
        if (blk == 0)
            for (int t = tid; t < 64 * NCLS; t += 512) out[t] = 0.0f;
    }

    // ---- all 70 gate-coefficient sets, one per thread ----
    if (tid < NCOEF) {
        const int layer = tid / 14, q = tid % 14;
        const int pidx = (layer < 4) ? layer * 42 + q * 3 : 168 + q * 2;
        float a1 = 0.5f * xb[pidx], a2 = 0.5f * xb[pidx + 1];
        float s1, c1, s2, c2;
        sincosf(a1, &s1, &c1);
        sincosf(a2, &s2, &c2);
        float A00r =  c2 * c1, A00i =  s2 * s1;
        float A01r = -s2 * c1, A01i = -c2 * s1;
        float A10r =  s2 * c1, A10i = -c2 * s1;
        float A11r =  c2 * c1, A11i = -s2 * s1;
        float U0, U1, U2, U3, U4, U5, U6, U7;
        if (layer < 4) {
            float a3 = 0.5f * xb[pidx + 2]; float s3, c3; sincosf(a3, &s3, &c3);
            U0 = c3 * A00r + s3 * A00i; U1 = c3 * A00i - s3 * A00r;
            U2 = c3 * A01r + s3 * A01i; U3 = c3 * A01i - s3 * A01r;
            U4 = c3 * A10r - s3 * A10i; U5 = c3 * A10i + s3 * A10r;
            U6 = c3 * A11r - s3 * A11i; U7 = c3 * A11i + s3 * A11r;
        } else {
            U0 = A00r; U1 = A00i; U2 = A01r; U3 = A01i;
            U4 = A10r; U5 = A10i; U6 = A11r; U7 = A11i;
        }
        uc[tid][0] = U0; uc[tid][1] = U1; uc[tid][2] = U2; uc[tid][3] = U3;
        uc[tid][4] = U4; uc[tid][5] = U5; uc[tid][6] = U6; uc[tid][7] = U7;
    }
    __syncthreads();

    float ar[8], ai[8];
    if constexpr (SEG == 0) {
        // ---- chi=4 TT init (helpers verified r14), partitioned for this layout:
        // shared prefix sites 0..6; per-k middle 7..10 (k = h bits 8..10);
        // suffix base 13 + wsteps 12,11.
        const int ghs = hbase ^ (hbase >> 1);     // bits 0..6, 11..13 k-independent
        float Rr[4], Ri[4];
        #pragma unroll
        for (int j = 0; j < 4; ++j) { Rr[j] = 1.0f; Ri[j] = 0.0f; }
        #pragma unroll
        for (int bp = 0; bp < 7; ++bp)
            tt4_step(Rr, Ri, &uc[28 + (13 - bp)][0], &uc[14 + (13 - bp)][0],
                     &uc[13 - bp][0], (ghs >> bp) & 1);
        float Wr[4], Wi[4];
        {
            const int b13 = (ghs >> 13) & 1;
            const float* V2u = &uc[28][0];
            const float* V1u = &uc[14][0];
            const float* Pu  = &uc[0][0];
            #pragma unroll
            for (int c2 = 0; c2 < 2; ++c2) {
                const float v2r = V2u[b13 * 4 + c2 * 2], v2i = V2u[b13 * 4 + c2 * 2 + 1];
                #pragma unroll
                for (int c = 0; c < 2; ++c) {
                    const float v1r = V1u[c2 * 4 + c * 2], v1i = V1u[c2 * 4 + c * 2 + 1];
                    const float pr = Pu[c * 4], pi = Pu[c * 4 + 1];
                    const float tr = v1r * pr - v1i * pi, ti = v1r * pi + v1i * pr;
                    Wr[c2 * 2 + c] = v2r * tr - v2i * ti;
                    Wi[c2 * 2 + c] = v2r * ti + v2i * tr;
                }
            }
        }
        #pragma unroll
        for (int bp = 12; bp >= 11; --bp)
            tt4_wstep(Wr, Wi, &uc[28 + (13 - bp)][0], &uc[14 + (13 - bp)][0],
                      &uc[13 - bp][0], (ghs >> bp) & 1);
        #pragma unroll
        for (int k = 0; k < 8; ++k) {
            const int hh = hbase | (k << 8);
            const int ghk = hh ^ (hh >> 1);
            float rr[4], ri[4];
            #pragma unroll
            for (int j = 0; j < 4; ++j) { rr[j] = Rr[j]; ri[j] = Ri[j]; }
            #pragma unroll
            for (int bp = 7; bp <= 10; ++bp)
                tt4_step(rr, ri, &uc[28 + (13 - bp)][0], &uc[14 + (13 - bp)][0],
                         &uc[13 - bp][0], (ghk >> bp) & 1);
            float dr = 0.0f, di = 0.0f;
            #pragma unroll
            for (int j = 0; j < 4; ++j) {
                dr += rr[j] * Wr[j] - ri[j] * Wi[j];
                di += rr[j] * Wi[j] + ri[j] * Wr[j];
            }
            ar[k] = dr; ai[k] = di;
        }
    } else {
        #pragma unroll
        for (int k = 0; k < 8; ++k) {
            const int idx = (e << 14) | ((k & 3) << 12)
                          | (((p << 4) | (w << 1) | (k >> 2)) << 6) | l;
            float2 v = gin[idx];
            ar[k] = v.x; ai[k] = v.y;
        }
    }

    do_gates<SEG>(ar, ai, uc, lds_r, lds_i, tid, hbase);

    if constexpr (SEG == 0) {
        #pragma unroll
        for (int k = 0; k < 8; ++k) {
            const int idx = (e << 14) | (p << 12) | (((w << 3) | k) << 6) | l;
            gout[idx] = make_float2(ar[k], ai[k]);
        }
    } else {
        // ---- measurement: E_q = sum |amp|^2 * (-1)^parity(h & mu[q]) ----
        // layout-1 k' bits of mu: kmu = (mu_8)<<2 | mu_1<<1 | mu_0
        float eq[NQ];
        #pragma unroll
        for (int q = 0; q < NQ; ++q) eq[q] = 0.0f;
        #pragma unroll
        for (int k = 0; k < 8; ++k) {
            float p2 = ar[k] * ar[k] + ai[k] * ai[k];
            #pragma unroll
            for (int q = 0; q < NQ; ++q) {
                const int kmu = (((TAB.mu[q] >> 8) & 1) << 2) | (TAB.mu[q] & 3);
                if (__popc(k & kmu) & 1) eq[q] -= p2; else eq[q] += p2;
            }
        }
        #pragma unroll
        for (int q = 0; q < NQ; ++q) {
            float v = (__popc(hbase & TAB.mu[q]) & 1) ? -eq[q] : eq[q];
            #pragma unroll
            for (int off = 32; off > 0; off >>= 1) v += __shfl_down(v, off, 64);
            eq[q] = v;
        }
        if (l == 0) {
            #pragma unroll
            for (int q = 0; q < NQ; ++q) red[w][q] = eq[q];
        }
        __syncthreads();
        if (tid < NQ) {
            float s = 0.0f;
            #pragma unroll
            for (int ww = 0; ww < 8; ++ww) s += red[ww][tid];
            eqv[tid] = s;
        }
        __syncthreads();
        // ---- head folded in: atomicAdd partial dot products (out zeroed in SEG 0) ----
        if (tid < NCLS) {
            float acc = (p == 0) ? bias[tid] : 0.0f;
            #pragma unroll
            for (int q = 0; q < NQ; ++q) acc += W[tid * NQ + q] * eqv[q];
            atomicAdd(&out[e * NCLS + tid], acc);   // device-scope, cross-XCD safe
        }
    }
}

extern "C" void kernel_launch(void* const* d_in, const int* in_sizes, int n_in,
                              void* d_out, int out_size, void* d_ws, size_t ws_size,
                              hipStream_t stream)
{
    const float* x    = (const float*)d_in[0];   // (64, 196)
    const float* W    = (const float*)d_in[1];   // (10, 14)
    const float* bias = (const float*)d_in[2];   // (10,)
    float*       out  = (float*)d_out;           // (64, 10)

    float2* bufA = (float2*)d_ws;                // one 8 MB state buffer
    (void)ws_size;  // observed 268 MB >> 8 MB needed

    hipLaunchKernelGGL(qvc_seg<0>, dim3(256), dim3(512), 0, stream,
                       x, (const float2*)nullptr, bufA, W, bias, out);
    hipLaunchKernelGGL(qvc_seg<1>, dim3(256), dim3(512), 0, stream,
                       x, bufA, (float2*)nullptr, W, bias, out);
}